// Round 9
// baseline (15669.298 us; speedup 1.0000x reference)
//
#include <hip/hip_runtime.h>
#include <hip/hip_bf16.h>

// Problem constants
#define B_   512
#define T_   256
#define F_   256
#define E_   256
#define H_   256
#define G4_  1024      // 4*H
#define K_   768       // H + E + F  (q | r | x)
#define NT   512       // threads per block (8 waves)
#define NBLK 256       // main kernel blocks (2 molecules each, sequential)

typedef __attribute__((ext_vector_type(8))) short short8;
typedef __attribute__((ext_vector_type(8))) unsigned short ushort8v;
typedef __attribute__((ext_vector_type(4))) unsigned short ushort4v;
typedef __attribute__((ext_vector_type(4))) float f32x4;

__device__ __forceinline__ float bf2f(unsigned int u) {
  union { unsigned int i; float f; } v; v.i = u << 16; return v.f;
}
__device__ __forceinline__ unsigned short f2bf(float f) {
  union { __hip_bfloat16 h; unsigned short u; } v;
  v.h = __float2bfloat16(f); return v.u;
}
__device__ __forceinline__ float sigm(float x) { return 1.f / (1.f + __expf(-x)); }
__device__ __forceinline__ float tanh_fast(float x) { return 1.f - 2.f / (1.f + __expf(2.f * x)); }

// ---------------- setup: pack weights into MFMA B-fragment streams ----------------
// B-frag layout (16x16x32 bf16): lane holds B[n' = lane&15][k = (lane>>4)*8 + j]
// Bg gate-fused mapping: frag (w*8+nt)*24+kt covers rows
//   n = (nt>>1)*256 + w*32 + (nt&1)*16 + (lane&15)   (gate = nt>>1, wave-local h block)
__global__ void setup_pack(const float* __restrict__ W_ih, const float* __restrict__ W_hh,
                           const float* __restrict__ b_ih, const float* __restrict__ b_hh,
                           const float* __restrict__ W_att, const float* __restrict__ W_embed,
                           unsigned short* __restrict__ Bg, unsigned short* __restrict__ Bx,
                           unsigned short* __restrict__ Ba, unsigned short* __restrict__ We,
                           float* __restrict__ bcomb) {
  int idx = blockIdx.x * blockDim.x + threadIdx.x;
  if (idx < G4_ * K_) {
    int o = idx, j = o & 7, lane = (o >> 3) & 63, rem = o >> 9;
    int kt = rem % 24, ntw = rem / 24;
    int w = ntw >> 3, nt = ntw & 7;
    int n = (nt >> 1) * 256 + w * 32 + (nt & 1) * 16 + (lane & 15);
    int k = kt * 32 + ((lane >> 4) << 3) + j;
    float v = W_ih[n * K_ + k] + (k < H_ ? W_hh[n * H_ + k] : 0.f);
    Bg[o] = f2bf(v);
    return;
  }
  idx -= G4_ * K_;
  if (idx < G4_ * F_) {
    int o = idx, j = o & 7, lane = (o >> 3) & 63, rem = o >> 9;
    int kt = rem & 7, ntw = rem >> 3;
    int n = ntw * 16 + (lane & 15);
    int k = kt * 32 + ((lane >> 4) << 3) + j;
    Bx[o] = f2bf(W_ih[n * K_ + 512 + k]);
    return;
  }
  idx -= G4_ * F_;
  if (idx < E_ * H_) {
    int o = idx, j = o & 7, lane = (o >> 3) & 63, rem = o >> 9;
    int kt = rem & 7, ntw = rem >> 3;
    int n = ntw * 16 + (lane & 15), k = kt * 32 + ((lane >> 4) << 3) + j;
    Ba[o] = f2bf(W_att[n * H_ + k]);
    return;
  }
  idx -= E_ * H_;
  if (idx < E_ * F_) {
    int o = idx, j = o & 7, lane = (o >> 3) & 63, rem = o >> 9;
    int kt = rem & 7, ntw = rem >> 3;
    int n = ntw * 16 + (lane & 15), k = kt * 32 + ((lane >> 4) << 3) + j;
    We[o] = f2bf(W_embed[n * F_ + k]);
    return;
  }
  idx -= E_ * F_;
  if (idx < G4_) bcomb[idx] = b_ih[idx] + b_hh[idx];
}

// ---------------- deterministic rank sort of lengths -> perm ----------------
__global__ void sort_kernel(const int* __restrict__ lengths, int* __restrict__ perm) {
  __shared__ int lens[B_];
  int tid = threadIdx.x;
  lens[tid] = lengths[tid];
  __syncthreads();
  int L = lens[tid], pos = 0;
  for (int i = 0; i < B_; ++i) {
    int li = lens[i];
    pos += (li < L) || (li == L && i < tid);
  }
  perm[pos] = tid;
}

// ---------------- gx precompute: gx[b][t][n] = sum_f W_x[n][f] * x[b][t][f] (bf16) ----
// gxw stays in ORIGINAL n order (independent of Bg's fused packing).
__global__ __launch_bounds__(256)
void gx_kernel(const float* __restrict__ features, const unsigned short* __restrict__ Bx,
               unsigned short* __restrict__ gxw) {
  __shared__ unsigned short featL[T_][264];   // 135168 B
  const int b = blockIdx.x;
  const int tid = threadIdx.x, w = tid >> 6, lane = tid & 63;
  const float* fb = features + (size_t)b * T_ * F_;
  for (int c4 = 0; c4 < 64; ++c4) {
    float4 v = *reinterpret_cast<const float4*>(fb + (size_t)tid * F_ + c4 * 4);
    featL[tid][c4 * 4 + 0] = f2bf(v.x);
    featL[tid][c4 * 4 + 1] = f2bf(v.y);
    featL[tid][c4 * 4 + 2] = f2bf(v.z);
    featL[tid][c4 * 4 + 3] = f2bf(v.w);
  }
  __syncthreads();
  const short8* BX = reinterpret_cast<const short8*>(Bx);
  for (int nt = w; nt < 64; nt += 4) {
    short8 Bf[8];
    #pragma unroll
    for (int kt = 0; kt < 8; ++kt) Bf[kt] = BX[(nt * 8 + kt) * 64 + lane];
    for (int mt = 0; mt < 16; ++mt) {
      f32x4 acc = f32x4{0.f, 0.f, 0.f, 0.f};
      #pragma unroll
      for (int kt = 0; kt < 8; ++kt) {
        short8 a = *reinterpret_cast<const short8*>(
            &featL[mt * 16 + (lane & 15)][kt * 32 + ((lane >> 4) << 3)]);
        acc = __builtin_amdgcn_mfma_f32_16x16x32_bf16(a, Bf[kt], acc, 0, 0, 0);
      }
      #pragma unroll
      for (int reg = 0; reg < 4; ++reg) {
        int t = mt * 16 + (lane >> 4) * 4 + reg;
        gxw[((size_t)b * T_ + t) * G4_ + nt * 16 + (lane & 15)] = f2bf(acc[reg]);
      }
    }
  }
}

// ---------------- main: 256 blocks, 2 length-paired molecules sequentially ----------------
// LDS (147 KB) limits residency to 1 block/CU regardless of VGPRs, so declare
// min-waves=1: the 128-VGPR cap from (NT,2) was causing scratch spill (R7/R8).
template <int USE_GX>
__global__ __launch_bounds__(NT, 1)
void mol_kernel(const float* __restrict__ features, const int* __restrict__ lengths,
                const int* __restrict__ perm,
                const unsigned short* __restrict__ Bg, const unsigned short* __restrict__ Ba,
                const unsigned short* __restrict__ We, const float* __restrict__ bcomb,
                const float* __restrict__ Wfin, const float* __restrict__ bfin,
                const float* __restrict__ q0, const float* __restrict__ c0,
                const float* __restrict__ r0, const unsigned short* __restrict__ gxw,
                float* __restrict__ out) {
  __shared__ __align__(16) unsigned short emb[T_][264];   // 135168 B
  __shared__ __align__(16) unsigned short qbuf[2][272];   // q double-buffer (bf16)
  __shared__ __align__(16) unsigned short qs[528];        // [r(256)|x(256)] bf16
  __shared__ __align__(16) unsigned short qpb[272];       // qp bf16
  __shared__ float esc[T_];
  __shared__ float rpart[8][264];                         // 8448 B
  __shared__ float redf[8];

  const int tid  = threadIdx.x;
  const int w    = tid >> 6;
  const int lane = tid & 63;
  const int l15  = lane & 15;
  const float bfinal = bfin[0];
  const int KTL = USE_GX ? 16 : 24;                       // gate K-tiles per step

  const short8* BW  = reinterpret_cast<const short8*>(Bg);
  const short8* BA  = reinterpret_cast<const short8*>(Ba);
  const short8* WE  = reinterpret_cast<const short8*>(We);
  const short8* qs8 = reinterpret_cast<const short8*>(qs);

  // W_att B-frags resident in VGPRs (constant across steps/molecules): 64 VGPR
  short8 barf0[8], barf1[8];
  #pragma unroll
  for (int kt = 0; kt < 8; ++kt) {
    barf0[kt] = BA[((2 * w + 0) * 8 + kt) * 64 + lane];
    barf1[kt] = BA[((2 * w + 1) * 8 + kt) * 64 + lane];
  }

  // per-lane persistent constants: gate biases (fused n-mapping) + W_final slice
  float biasr[8];
  #pragma unroll
  for (int nt = 0; nt < 8; ++nt)
    biasr[nt] = bcomb[(nt >> 1) * 256 + w * 32 + (nt & 1) * 16 + l15];
  const float wfr0 = Wfin[w * 32 + l15];
  const float wfr1 = Wfin[w * 32 + 16 + l15];

  for (int half = 0; half < 2; ++half) {
    const int b   = perm[half == 0 ? (int)blockIdx.x : (B_ - 1 - (int)blockIdx.x)];
    const int len = lengths[b];
    const float* featb = features + (size_t)b * T_ * F_;
    const unsigned short* gxb = USE_GX ? (gxw + (size_t)b * T_ * G4_) : nullptr;
    const int nmt = (len + 15) >> 4;

    // ---- init state ----
    float cst0 = c0[(size_t)b * H_ + w * 32 + l15];
    float cst1 = c0[(size_t)b * H_ + w * 32 + 16 + l15];
    if (tid < H_) {
      qbuf[0][tid] = f2bf(q0[(size_t)b * H_ + tid]);
      qs[tid]      = f2bf(r0[(size_t)b * E_ + tid]);
      esc[tid] = -3.0e38f;                       // rows never written stay -inf
      if (!USE_GX) qs[256 + tid] = f2bf(featb[tid]);   // x_0
    }

    // ---- embedding via MFMA into LDS: emb[t][e] for tiles with t < len ----
    for (int mt = 0; mt < nmt; ++mt) {
      f32x4 ea0 = f32x4{0.f, 0.f, 0.f, 0.f};
      f32x4 ea1 = f32x4{0.f, 0.f, 0.f, 0.f};
      #pragma unroll
      for (int kt = 0; kt < 8; ++kt) {
        const float* ap_ = featb + (size_t)(mt * 16 + l15) * F_ + kt * 32 + ((lane >> 4) << 3);
        float4 fa = *reinterpret_cast<const float4*>(ap_);
        float4 fb4 = *reinterpret_cast<const float4*>(ap_ + 4);
        short8 a;
        a[0] = (short)f2bf(fa.x);  a[1] = (short)f2bf(fa.y);
        a[2] = (short)f2bf(fa.z);  a[3] = (short)f2bf(fa.w);
        a[4] = (short)f2bf(fb4.x); a[5] = (short)f2bf(fb4.y);
        a[6] = (short)f2bf(fb4.z); a[7] = (short)f2bf(fb4.w);
        ea0 = __builtin_amdgcn_mfma_f32_16x16x32_bf16(a, WE[((2 * w + 0) * 8 + kt) * 64 + lane], ea0, 0, 0, 0);
        ea1 = __builtin_amdgcn_mfma_f32_16x16x32_bf16(a, WE[((2 * w + 1) * 8 + kt) * 64 + lane], ea1, 0, 0, 0);
      }
      #pragma unroll
      for (int reg = 0; reg < 4; ++reg) {
        int t = mt * 16 + (lane >> 4) * 4 + reg;
        emb[t][(2 * w + 0) * 16 + l15] = f2bf(ea0[reg]);
        emb[t][(2 * w + 1) * 16 + l15] = f2bf(ea1[reg]);
      }
    }

    // ---- recurrence ----
    for (int t = 0; t < len; ++t) {
      __syncthreads();   // B1: q(t)/r(t)/x(t), emb, esc ready

      const short8* qc8 = reinterpret_cast<const short8*>(qbuf[t & 1]);
      unsigned short* qnxt = qbuf[(t + 1) & 1];

      // early per-step loads (latency hidden under phase 1)
      unsigned short gxr[8];
      float xnext = 0.f;
      if (USE_GX) {
        const unsigned short* gp = gxb + (size_t)t * G4_;
        #pragma unroll
        for (int nt = 0; nt < 8; ++nt)
          gxr[nt] = gp[(nt >> 1) * 256 + w * 32 + (nt & 1) * 16 + l15];
      } else {
        if (tid < H_ && t + 1 < T_) xnext = featb[(size_t)(t + 1) * F_ + tid];
      }

      // phase 1: gates MFMA (bias in C[0]) fused with in-register LSTM
      {
        f32x4 acc[8];
        #pragma unroll
        for (int nt = 0; nt < 8; ++nt) acc[nt] = f32x4{biasr[nt], 0.f, 0.f, 0.f};
        short8 cur[8], nxt[8];
        #pragma unroll
        for (int nt = 0; nt < 8; ++nt) cur[nt] = BW[((w * 8 + nt) * 24 + 0) * 64 + lane];
        #pragma unroll
        for (int kt = 0; kt < KTL; ++kt) {
          if (kt + 1 < KTL) {
            #pragma unroll
            for (int nt = 0; nt < 8; ++nt) nxt[nt] = BW[((w * 8 + nt) * 24 + kt + 1) * 64 + lane];
          }
          short8 a = (kt < 8) ? qc8[kt * 4 + (lane >> 4)]
                              : qs8[(kt - 8) * 4 + (lane >> 4)];
          #pragma unroll
          for (int nt = 0; nt < 8; ++nt)
            acc[nt] = __builtin_amdgcn_mfma_f32_16x16x32_bf16(a, cur[nt], acc[nt], 0, 0, 0);
          #pragma unroll
          for (int nt = 0; nt < 8; ++nt) cur[nt] = nxt[nt];
        }
        // in-register LSTM: lane l<16 owns h0 = 32w+l (acc 0,2,4,6) and h1 = 32w+16+l (acc 1,3,5,7)
        if (lane < 16) {
          float i0 = acc[0][0], i1 = acc[1][0];
          float f0 = acc[2][0], f1 = acc[3][0];
          float g0 = acc[4][0], g1 = acc[5][0];
          float o0 = acc[6][0], o1 = acc[7][0];
          if (USE_GX) {
            i0 += bf2f(gxr[0]); i1 += bf2f(gxr[1]);
            f0 += bf2f(gxr[2]); f1 += bf2f(gxr[3]);
            g0 += bf2f(gxr[4]); g1 += bf2f(gxr[5]);
            o0 += bf2f(gxr[6]); o1 += bf2f(gxr[7]);
          }
          float cn0 = sigm(f0) * cst0 + sigm(i0) * tanh_fast(g0);
          float qn0 = sigm(o0) * tanh_fast(cn0);
          cst0 = cn0;
          float cn1 = sigm(f1) * cst1 + sigm(i1) * tanh_fast(g1);
          float qn1 = sigm(o1) * tanh_fast(cn1);
          cst1 = cn1;
          qnxt[w * 32 + l15]      = f2bf(qn0);
          qnxt[w * 32 + 16 + l15] = f2bf(qn1);
          float po = fmaxf(qn0, 0.f) * wfr0 + fmaxf(qn1, 0.f) * wfr1;
          po += __shfl_xor(po, 1); po += __shfl_xor(po, 2);
          po += __shfl_xor(po, 4); po += __shfl_xor(po, 8);
          if (lane == 0) redf[w] = po;
        }
      }
      __syncthreads();   // B2: qnew + redf ready

      // phase 3: out write + qp = W_att @ qnew (resident B-frags) -> qpb bf16
      if (tid == 0) {
        out[(size_t)b * T_ + t] = redf[0] + redf[1] + redf[2] + redf[3]
                                + redf[4] + redf[5] + redf[6] + redf[7] + bfinal;
      }
      {
        const short8* qn8 = reinterpret_cast<const short8*>(qnxt);
        f32x4 a0 = f32x4{0.f, 0.f, 0.f, 0.f};
        f32x4 a1 = f32x4{0.f, 0.f, 0.f, 0.f};
        #pragma unroll
        for (int kt = 0; kt < 8; ++kt) {
          short8 a = qn8[kt * 4 + (lane >> 4)];
          a0 = __builtin_amdgcn_mfma_f32_16x16x32_bf16(a, barf0[kt], a0, 0, 0, 0);
          a1 = __builtin_amdgcn_mfma_f32_16x16x32_bf16(a, barf1[kt], a1, 0, 0, 0);
        }
        if (lane < 16) {
          qpb[(2 * w + 0) * 16 + lane] = f2bf(a0[0]);
          qpb[(2 * w + 1) * 16 + lane] = f2bf(a1[0]);
        }
      }
      __syncthreads();   // B4: qpb ready

      // phase 4: scores via MFMA (A = emb rows from LDS, B = qp broadcast)
      {
        #pragma unroll
        for (int h4 = 0; h4 < 2; ++h4) {
          const int mt = 2 * w + h4;
          if (mt < nmt) {
            f32x4 acc = f32x4{0.f, 0.f, 0.f, 0.f};
            #pragma unroll
            for (int kt = 0; kt < 8; ++kt) {
              short8 a  = *reinterpret_cast<const short8*>(
                  &emb[mt * 16 + l15][kt * 32 + ((lane >> 4) << 3)]);
              short8 bq = *reinterpret_cast<const short8*>(
                  &qpb[kt * 32 + ((lane >> 4) << 3)]);
              acc = __builtin_amdgcn_mfma_f32_16x16x32_bf16(a, bq, acc, 0, 0, 0);
            }
            if (l15 == 0) {
              #pragma unroll
              for (int reg = 0; reg < 4; ++reg) {
                int tt = mt * 16 + (lane >> 4) * 4 + reg;
                esc[tt] = (tt < len) ? acc[reg] : -3.0e38f;
              }
            }
          }
        }
      }
      __syncthreads();   // B5: esc ready

      // phase 5: softmax (each wave computes all 256 p in registers)
      float rinv, p0, p1, p2, p3;
      {
        float v0 = esc[lane], v1 = esc[lane + 64], v2 = esc[lane + 128], v3 = esc[lane + 192];
        float m = fmaxf(fmaxf(v0, v1), fmaxf(v2, v3));
        #pragma unroll
        for (int s = 32; s >= 1; s >>= 1) m = fmaxf(m, __shfl_xor(m, s));
        p0 = __expf(v0 - m); p1 = __expf(v1 - m); p2 = __expf(v2 - m); p3 = __expf(v3 - m);
        float sv = p0 + p1 + p2 + p3;
        #pragma unroll
        for (int s = 32; s >= 1; s >>= 1) sv += __shfl_xor(sv, s);
        rinv = 1.f / sv;
      }

      // phase 6A: partial r — wave w owns t rows [32w, 32w+32); p via shuffle broadcast
      {
        const int t0 = w * 32;
        const int tmax = (t0 + 32 < len) ? (t0 + 32) : len;
        const int sbase = (w & 1) * 32;
        const int ksel = w >> 1;
        float vsel = (ksel == 0) ? p0 : (ksel == 1) ? p1 : (ksel == 2) ? p2 : p3;
        float r0a = 0.f, r1a = 0.f, r2a = 0.f, r3a = 0.f;
        for (int i = 0; t0 + i < tmax; ++i) {
          float p = __shfl(vsel, sbase + i);
          ushort4v ev = *reinterpret_cast<const ushort4v*>(&emb[t0 + i][lane * 4]);
          r0a += p * bf2f(ev[0]); r1a += p * bf2f(ev[1]);
          r2a += p * bf2f(ev[2]); r3a += p * bf2f(ev[3]);
        }
        f32x4 rv = {r0a, r1a, r2a, r3a};
        *reinterpret_cast<f32x4*>(&rpart[w][lane * 4]) = rv;
      }
      __syncthreads();   // B6: rpart ready

      // phase 6B: r[e] -> qs[0:256]; x prefetch -> qs[256:512] (fallback)
      if (tid < H_) {
        float s = 0.f;
        #pragma unroll
        for (int sl = 0; sl < 8; ++sl) s += rpart[sl][tid];
        qs[tid] = f2bf(s * rinv);
        if (!USE_GX) qs[256 + tid] = f2bf(xnext);
      }
      // loop-top barrier (B1) fences qs/qbuf writes
    }

    // zero padded outputs
    for (int tt = len + tid; tt < T_; tt += NT) out[(size_t)b * T_ + tt] = 0.f;
    __syncthreads();   // emb/qs/esc reuse fence before next molecule
  }
}

extern "C" void kernel_launch(void* const* d_in, const int* in_sizes, int n_in,
                              void* d_out, int out_size, void* d_ws, size_t ws_size,
                              hipStream_t stream) {
  const float* features = (const float*)d_in[0];
  const int*   lengths  = (const int*)d_in[1];
  const float* W_embed  = (const float*)d_in[2];
  const float* W_ih     = (const float*)d_in[3];
  const float* b_ih     = (const float*)d_in[4];
  const float* W_hh     = (const float*)d_in[5];
  const float* b_hh     = (const float*)d_in[6];
  const float* W_att    = (const float*)d_in[7];
  const float* W_final  = (const float*)d_in[8];
  const float* b_final  = (const float*)d_in[9];
  const float* q0       = (const float*)d_in[10];
  const float* c0       = (const float*)d_in[11];
  const float* r0       = (const float*)d_in[12];
  float* out = (float*)d_out;

  char* ws = (char*)d_ws;
  unsigned short* Bg    = (unsigned short*)(ws + 0);          // 1,572,864
  unsigned short* Bx    = (unsigned short*)(ws + 1572864);    //   524,288
  unsigned short* Ba    = (unsigned short*)(ws + 2097152);    //   131,072
  unsigned short* We    = (unsigned short*)(ws + 2228224);    //   131,072
  float*          bcomb = (float*)(ws + 2359296);             //     4,096
  int*            perm  = (int*)(ws + 2363392);               //     2,048
  unsigned short* gxw   = (unsigned short*)(ws + 2365440);    // 268,435,456
  const size_t need_gx = 2365440ull + 268435456ull;
  const int use_gx = (ws_size >= need_gx) ? 1 : 0;

  const int setup_elems = G4_ * K_ + G4_ * F_ + E_ * H_ + E_ * F_ + G4_;  // 1,180,672
  setup_pack<<<(setup_elems + 255) / 256, 256, 0, stream>>>(
      W_ih, W_hh, b_ih, b_hh, W_att, W_embed, Bg, Bx, Ba, We, bcomb);
  sort_kernel<<<1, B_, 0, stream>>>(lengths, perm);
  if (use_gx) {
    gx_kernel<<<B_, 256, 0, stream>>>(features, Bx, gxw);
    mol_kernel<1><<<NBLK, NT, 0, stream>>>(
        features, lengths, perm, Bg, Ba, We, bcomb,
        W_final, b_final, q0, c0, r0, gxw, out);
  } else {
    mol_kernel<0><<<NBLK, NT, 0, stream>>>(
        features, lengths, perm, Bg, Ba, We, bcomb,
        W_final, b_final, q0, c0, r0, gxw, out);
  }
}

// Round 10
// 3545.766 us; speedup vs baseline: 4.4192x; 4.4192x over previous
//
#include <hip/hip_runtime.h>
#include <hip/hip_bf16.h>

// Problem constants
#define B_   512
#define T_   256
#define F_   256
#define E_   256
#define H_   256
#define G4_  1024      // 4*H
#define K_   768       // H + E + F  (q | r | x)
#define NT   1024      // threads per block (16 waves)
#define NBLK 256       // main kernel blocks (2 molecules each, sequential)

typedef __attribute__((ext_vector_type(8))) short short8;
typedef __attribute__((ext_vector_type(8))) unsigned short ushort8v;
typedef __attribute__((ext_vector_type(4))) unsigned short ushort4v;
typedef __attribute__((ext_vector_type(4))) float f32x4;

__device__ __forceinline__ float bf2f(unsigned int u) {
  union { unsigned int i; float f; } v; v.i = u << 16; return v.f;
}
__device__ __forceinline__ unsigned short f2bf(float f) {
  union { __hip_bfloat16 h; unsigned short u; } v;
  v.h = __float2bfloat16(f); return v.u;
}
__device__ __forceinline__ float sigm(float x) { return 1.f / (1.f + __expf(-x)); }
__device__ __forceinline__ float tanh_fast(float x) { return 1.f - 2.f / (1.f + __expf(2.f * x)); }

// ---------------- setup: pack weights into MFMA B-fragment streams ----------------
// B-frag layout (16x16x32 bf16): lane holds B[n = lane&15][k = (lane>>4)*8 + j]
// (identical layouts to round 6 — only the consumer wave-indexing changed)
__global__ void setup_pack(const float* __restrict__ W_ih, const float* __restrict__ W_hh,
                           const float* __restrict__ b_ih, const float* __restrict__ b_hh,
                           const float* __restrict__ W_att, const float* __restrict__ W_embed,
                           unsigned short* __restrict__ Bg, unsigned short* __restrict__ Bx,
                           unsigned short* __restrict__ Ba, unsigned short* __restrict__ We,
                           float* __restrict__ bcomb) {
  int idx = blockIdx.x * blockDim.x + threadIdx.x;
  if (idx < G4_ * K_) {
    int o = idx, j = o & 7, lane = (o >> 3) & 63, rem = o >> 9;
    int kt = rem % 24, ntw = rem / 24;
    int n = ntw * 16 + (lane & 15);
    int k = kt * 32 + ((lane >> 4) << 3) + j;
    float v = W_ih[n * K_ + k] + (k < H_ ? W_hh[n * H_ + k] : 0.f);
    Bg[o] = f2bf(v);
    return;
  }
  idx -= G4_ * K_;
  if (idx < G4_ * F_) {
    int o = idx, j = o & 7, lane = (o >> 3) & 63, rem = o >> 9;
    int kt = rem & 7, ntw = rem >> 3;
    int n = ntw * 16 + (lane & 15);
    int k = kt * 32 + ((lane >> 4) << 3) + j;
    Bx[o] = f2bf(W_ih[n * K_ + 512 + k]);
    return;
  }
  idx -= G4_ * F_;
  if (idx < E_ * H_) {
    int o = idx, j = o & 7, lane = (o >> 3) & 63, rem = o >> 9;
    int kt = rem & 7, ntw = rem >> 3;
    int n = ntw * 16 + (lane & 15), k = kt * 32 + ((lane >> 4) << 3) + j;
    Ba[o] = f2bf(W_att[n * H_ + k]);
    return;
  }
  idx -= E_ * H_;
  if (idx < E_ * F_) {
    int o = idx, j = o & 7, lane = (o >> 3) & 63, rem = o >> 9;
    int kt = rem & 7, ntw = rem >> 3;
    int n = ntw * 16 + (lane & 15), k = kt * 32 + ((lane >> 4) << 3) + j;
    We[o] = f2bf(W_embed[n * F_ + k]);
    return;
  }
  idx -= E_ * F_;
  if (idx < G4_) bcomb[idx] = b_ih[idx] + b_hh[idx];
}

// ---------------- deterministic rank sort of lengths -> perm ----------------
__global__ void sort_kernel(const int* __restrict__ lengths, int* __restrict__ perm) {
  __shared__ int lens[B_];
  int tid = threadIdx.x;
  lens[tid] = lengths[tid];
  __syncthreads();
  int L = lens[tid], pos = 0;
  for (int i = 0; i < B_; ++i) {
    int li = lens[i];
    pos += (li < L) || (li == L && i < tid);
  }
  perm[pos] = tid;
}

// ---------------- gx precompute: gx[b][t][n] = sum_f W_x[n][f] * x[b][t][f] (bf16) ----
__global__ __launch_bounds__(256)
void gx_kernel(const float* __restrict__ features, const unsigned short* __restrict__ Bx,
               unsigned short* __restrict__ gxw) {
  __shared__ unsigned short featL[T_][264];   // 135168 B
  const int b = blockIdx.x;
  const int tid = threadIdx.x, w = tid >> 6, lane = tid & 63;
  const float* fb = features + (size_t)b * T_ * F_;
  for (int c4 = 0; c4 < 64; ++c4) {
    float4 v = *reinterpret_cast<const float4*>(fb + (size_t)tid * F_ + c4 * 4);
    featL[tid][c4 * 4 + 0] = f2bf(v.x);
    featL[tid][c4 * 4 + 1] = f2bf(v.y);
    featL[tid][c4 * 4 + 2] = f2bf(v.z);
    featL[tid][c4 * 4 + 3] = f2bf(v.w);
  }
  __syncthreads();
  const short8* BX = reinterpret_cast<const short8*>(Bx);
  for (int nt = w; nt < 64; nt += 4) {
    short8 Bf[8];
    #pragma unroll
    for (int kt = 0; kt < 8; ++kt) Bf[kt] = BX[(nt * 8 + kt) * 64 + lane];
    for (int mt = 0; mt < 16; ++mt) {
      f32x4 acc = f32x4{0.f, 0.f, 0.f, 0.f};
      #pragma unroll
      for (int kt = 0; kt < 8; ++kt) {
        short8 a = *reinterpret_cast<const short8*>(
            &featL[mt * 16 + (lane & 15)][kt * 32 + ((lane >> 4) << 3)]);
        acc = __builtin_amdgcn_mfma_f32_16x16x32_bf16(a, Bf[kt], acc, 0, 0, 0);
      }
      #pragma unroll
      for (int reg = 0; reg < 4; ++reg) {
        int t = mt * 16 + (lane >> 4) * 4 + reg;
        gxw[((size_t)b * T_ + t) * G4_ + nt * 16 + (lane & 15)] = f2bf(acc[reg]);
      }
    }
  }
}

// ---------------- main: 256 blocks x 16 waves, 2 length-paired molecules sequentially ----
// Same math/phases as round 6 (3.27 ms verified) redistributed over 16 waves:
// per-phase wall time ~halves, per-wave register state shrinks. No unroll pragma on
// the kt weight-stream loop (R7-R9 lesson: forced unroll -> scratch demotion -> 28 GB).
template <int USE_GX>
__global__ __launch_bounds__(NT)
void mol_kernel(const float* __restrict__ features, const int* __restrict__ lengths,
                const int* __restrict__ perm,
                const unsigned short* __restrict__ Bg, const unsigned short* __restrict__ Ba,
                const unsigned short* __restrict__ We, const float* __restrict__ bcomb,
                const float* __restrict__ Wfin, const float* __restrict__ bfin,
                const float* __restrict__ q0, const float* __restrict__ c0,
                const float* __restrict__ r0, const unsigned short* __restrict__ gxw,
                float* __restrict__ out) {
  __shared__ __align__(16) unsigned short emb[T_][264];   // 135168 B
  __shared__ __align__(16) unsigned short qs[784];        // [q|r|(x)] bf16
  __shared__ __align__(16) unsigned short qpb[272];       // qp bf16
  __shared__ float gates[G4_];
  __shared__ float esc[T_];
  __shared__ float rpart[16][264];                        // 16896 B
  __shared__ float redf[16];

  const int tid  = threadIdx.x;
  const int w    = tid >> 6;          // 0..15
  const int lane = tid & 63;
  const int l15  = lane & 15;
  const float bfinal = bfin[0];
  const int KTL = USE_GX ? 16 : 24;   // gate K-tiles per step

  // per-thread constants (replaces wf/bco LDS arrays)
  float wfr = 0.f, bc0 = 0.f, bc1 = 0.f, bc2 = 0.f, bc3 = 0.f;
  if (tid < H_) {
    wfr = Wfin[tid];
    bc0 = bcomb[tid]; bc1 = bcomb[H_ + tid];
    bc2 = bcomb[2 * H_ + tid]; bc3 = bcomb[3 * H_ + tid];
  }

  const short8* BW  = reinterpret_cast<const short8*>(Bg);
  const short8* BA  = reinterpret_cast<const short8*>(Ba);
  const short8* WE  = reinterpret_cast<const short8*>(We);
  const short8* qs8 = reinterpret_cast<const short8*>(qs);

  // W_att B-frags resident: wave w owns e-tile w (8 frags = 32 VGPR)
  short8 barf[8];
  #pragma unroll
  for (int kt = 0; kt < 8; ++kt) barf[kt] = BA[(w * 8 + kt) * 64 + lane];

  for (int half = 0; half < 2; ++half) {
    const int b   = perm[half == 0 ? (int)blockIdx.x : (B_ - 1 - (int)blockIdx.x)];
    const int len = lengths[b];
    const float* featb = features + (size_t)b * T_ * F_;
    const unsigned short* gxb = USE_GX ? (gxw + (size_t)b * T_ * G4_) : nullptr;
    const int nmt = (len + 15) >> 4;

    // ---- init state ----
    float cstr = 0.f;
    if (tid < H_) {
      cstr = c0[(size_t)b * H_ + tid];
      qs[tid]       = f2bf(q0[(size_t)b * H_ + tid]);
      qs[H_ + tid]  = f2bf(r0[(size_t)b * E_ + tid]);
      esc[tid] = -3.0e38f;                       // rows never written stay -inf
      if (!USE_GX) qs[512 + tid] = f2bf(featb[tid]);   // x_0
    }

    // ---- embedding via MFMA into LDS: wave w owns e-tile w ----
    for (int mt = 0; mt < nmt; ++mt) {
      f32x4 ea = f32x4{0.f, 0.f, 0.f, 0.f};
      #pragma unroll
      for (int kt = 0; kt < 8; ++kt) {
        const float* ap_ = featb + (size_t)(mt * 16 + l15) * F_ + kt * 32 + ((lane >> 4) << 3);
        float4 fa = *reinterpret_cast<const float4*>(ap_);
        float4 fb4 = *reinterpret_cast<const float4*>(ap_ + 4);
        short8 a;
        a[0] = (short)f2bf(fa.x);  a[1] = (short)f2bf(fa.y);
        a[2] = (short)f2bf(fa.z);  a[3] = (short)f2bf(fa.w);
        a[4] = (short)f2bf(fb4.x); a[5] = (short)f2bf(fb4.y);
        a[6] = (short)f2bf(fb4.z); a[7] = (short)f2bf(fb4.w);
        ea = __builtin_amdgcn_mfma_f32_16x16x32_bf16(a, WE[(w * 8 + kt) * 64 + lane], ea, 0, 0, 0);
      }
      #pragma unroll
      for (int reg = 0; reg < 4; ++reg) {
        int t = mt * 16 + (lane >> 4) * 4 + reg;
        emb[t][w * 16 + l15] = f2bf(ea[reg]);
      }
    }

    // ---- recurrence ----
    for (int t = 0; t < len; ++t) {
      __syncthreads();   // B1: qs(t), emb, esc ready

      // early per-step global loads (latency hidden under phase 1)
      unsigned short gxu0 = 0, gxu1 = 0, gxu2 = 0, gxu3 = 0;
      float xnext = 0.f;
      if (USE_GX) {
        if (tid < H_) {
          const unsigned short* gp = gxb + (size_t)t * G4_ + tid;
          gxu0 = gp[0]; gxu1 = gp[256]; gxu2 = gp[512]; gxu3 = gp[768];
        }
      } else {
        if (tid < H_ && t + 1 < T_) xnext = featb[(size_t)(t + 1) * F_ + tid];
      }

      // phase 1: gates MFMA; wave w covers gate-row tiles ntw = w*4 + (0..3)
      {
        f32x4 acc[4];
        #pragma unroll
        for (int nt = 0; nt < 4; ++nt) acc[nt] = f32x4{0.f, 0.f, 0.f, 0.f};
        short8 cur[4], nxt[4];
        #pragma unroll
        for (int nt = 0; nt < 4; ++nt) cur[nt] = BW[((w * 4 + nt) * 24 + 0) * 64 + lane];
        for (int kt = 0; kt < KTL; ++kt) {    // NO unroll pragma (spill hazard)
          if (kt + 1 < KTL) {
            #pragma unroll
            for (int nt = 0; nt < 4; ++nt) nxt[nt] = BW[((w * 4 + nt) * 24 + kt + 1) * 64 + lane];
          }
          short8 a = qs8[kt * 4 + (lane >> 4)];
          #pragma unroll
          for (int nt = 0; nt < 4; ++nt)
            acc[nt] = __builtin_amdgcn_mfma_f32_16x16x32_bf16(a, cur[nt], acc[nt], 0, 0, 0);
          #pragma unroll
          for (int nt = 0; nt < 4; ++nt) cur[nt] = nxt[nt];
        }
        if (lane < 16) {
          #pragma unroll
          for (int nt = 0; nt < 4; ++nt) gates[w * 64 + nt * 16 + lane] = acc[nt][0];
        }
      }
      __syncthreads();   // B2: gates ready

      // phase 2: LSTM elementwise (tid<256), q -> qs[0:256], out-partial
      if (tid < H_) {
        float ig = gates[tid]           + bc0;
        float fg = gates[H_ + tid]      + bc1;
        float gg = gates[2 * H_ + tid]  + bc2;
        float og = gates[3 * H_ + tid]  + bc3;
        if (USE_GX) {
          ig += bf2f(gxu0); fg += bf2f(gxu1); gg += bf2f(gxu2); og += bf2f(gxu3);
        }
        float cn = sigm(fg) * cstr + sigm(ig) * tanh_fast(gg);
        float qn = sigm(og) * tanh_fast(cn);
        cstr = cn;
        qs[tid] = f2bf(qn);
        float po = fmaxf(qn, 0.f) * wfr;
        #pragma unroll
        for (int s = 32; s >= 1; s >>= 1) po += __shfl_xor(po, s);
        if (lane == 0) redf[w] = po;
      } else if (lane == 0) {
        redf[w] = 0.f;
      }
      __syncthreads();   // B3: qnew + redf ready

      // phase 3: out write + qp = W_att @ qnew (resident B-frags) -> qpb bf16
      if (tid == 0) {
        float s = 0.f;
        #pragma unroll
        for (int i = 0; i < 16; ++i) s += redf[i];
        out[(size_t)b * T_ + t] = s + bfinal;
      }
      {
        f32x4 a0 = f32x4{0.f, 0.f, 0.f, 0.f};
        #pragma unroll
        for (int kt = 0; kt < 8; ++kt) {
          short8 a = qs8[kt * 4 + (lane >> 4)];
          a0 = __builtin_amdgcn_mfma_f32_16x16x32_bf16(a, barf[kt], a0, 0, 0, 0);
        }
        if (lane < 16) qpb[w * 16 + lane] = f2bf(a0[0]);
      }
      __syncthreads();   // B4: qpb ready

      // phase 4: scores via MFMA; wave w owns t-tile w
      {
        const int mt = w;
        if (mt < nmt) {
          f32x4 acc = f32x4{0.f, 0.f, 0.f, 0.f};
          #pragma unroll
          for (int kt = 0; kt < 8; ++kt) {
            short8 a  = *reinterpret_cast<const short8*>(
                &emb[mt * 16 + l15][kt * 32 + ((lane >> 4) << 3)]);
            short8 bq = *reinterpret_cast<const short8*>(
                &qpb[kt * 32 + ((lane >> 4) << 3)]);
            acc = __builtin_amdgcn_mfma_f32_16x16x32_bf16(a, bq, acc, 0, 0, 0);
          }
          if (l15 == 0) {
            #pragma unroll
            for (int reg = 0; reg < 4; ++reg) {
              int tt = mt * 16 + (lane >> 4) * 4 + reg;
              esc[tt] = (tt < len) ? acc[reg] : -3.0e38f;
            }
          }
        }
      }
      __syncthreads();   // B5: esc ready

      // phase 5: softmax (each wave computes all 256 p in registers)
      float rinv, p0, p1, p2, p3;
      {
        float v0 = esc[lane], v1 = esc[lane + 64], v2 = esc[lane + 128], v3 = esc[lane + 192];
        float m = fmaxf(fmaxf(v0, v1), fmaxf(v2, v3));
        #pragma unroll
        for (int s = 32; s >= 1; s >>= 1) m = fmaxf(m, __shfl_xor(m, s));
        p0 = __expf(v0 - m); p1 = __expf(v1 - m); p2 = __expf(v2 - m); p3 = __expf(v3 - m);
        float sv = p0 + p1 + p2 + p3;
        #pragma unroll
        for (int s = 32; s >= 1; s >>= 1) sv += __shfl_xor(sv, s);
        rinv = 1.f / sv;
      }

      // phase 6A: partial r — wave w owns t rows [16w, 16w+16); p via shuffle broadcast
      {
        const int t0 = w * 16;
        const int tmax = (t0 + 16 < len) ? (t0 + 16) : len;
        const int sbase = (w & 3) * 16;
        const int ksel = w >> 2;
        float vsel = (ksel == 0) ? p0 : (ksel == 1) ? p1 : (ksel == 2) ? p2 : p3;
        float r0a = 0.f, r1a = 0.f, r2a = 0.f, r3a = 0.f;
        for (int i = 0; t0 + i < tmax; ++i) {
          float p = __shfl(vsel, sbase + i);
          ushort4v ev = *reinterpret_cast<const ushort4v*>(&emb[t0 + i][lane * 4]);
          r0a += p * bf2f(ev[0]); r1a += p * bf2f(ev[1]);
          r2a += p * bf2f(ev[2]); r3a += p * bf2f(ev[3]);
        }
        f32x4 rv = {r0a, r1a, r2a, r3a};
        *reinterpret_cast<f32x4*>(&rpart[w][lane * 4]) = rv;
      }
      __syncthreads();   // B6: rpart ready

      // phase 6B: r[e] = (sum_slices) * rinv -> qs[256+e]; x prefetch (fallback)
      if (tid < H_) {
        float s = 0.f;
        #pragma unroll
        for (int sl = 0; sl < 16; ++sl) s += rpart[sl][tid];
        qs[H_ + tid] = f2bf(s * rinv);
        if (!USE_GX) qs[512 + tid] = f2bf(xnext);
      }
      // loop-top barrier (B1) fences qs writes
    }

    // zero padded outputs
    for (int tt = len + tid; tt < T_; tt += NT) out[(size_t)b * T_ + tt] = 0.f;
    __syncthreads();   // emb/qs/esc reuse fence before next molecule
  }
}

extern "C" void kernel_launch(void* const* d_in, const int* in_sizes, int n_in,
                              void* d_out, int out_size, void* d_ws, size_t ws_size,
                              hipStream_t stream) {
  const float* features = (const float*)d_in[0];
  const int*   lengths  = (const int*)d_in[1];
  const float* W_embed  = (const float*)d_in[2];
  const float* W_ih     = (const float*)d_in[3];
  const float* b_ih     = (const float*)d_in[4];
  const float* W_hh     = (const float*)d_in[5];
  const float* b_hh     = (const float*)d_in[6];
  const float* W_att    = (const float*)d_in[7];
  const float* W_final  = (const float*)d_in[8];
  const float* b_final  = (const float*)d_in[9];
  const float* q0       = (const float*)d_in[10];
  const float* c0       = (const float*)d_in[11];
  const float* r0       = (const float*)d_in[12];
  float* out = (float*)d_out;

  char* ws = (char*)d_ws;
  unsigned short* Bg    = (unsigned short*)(ws + 0);          // 1,572,864
  unsigned short* Bx    = (unsigned short*)(ws + 1572864);    //   524,288
  unsigned short* Ba    = (unsigned short*)(ws + 2097152);    //   131,072
  unsigned short* We    = (unsigned short*)(ws + 2228224);    //   131,072
  float*          bcomb = (float*)(ws + 2359296);             //     4,096
  int*            perm  = (int*)(ws + 2363392);               //     2,048
  unsigned short* gxw   = (unsigned short*)(ws + 2365440);    // 268,435,456
  const size_t need_gx = 2365440ull + 268435456ull;
  const int use_gx = (ws_size >= need_gx) ? 1 : 0;

  const int setup_elems = G4_ * K_ + G4_ * F_ + E_ * H_ + E_ * F_ + G4_;  // 1,180,672
  setup_pack<<<(setup_elems + 255) / 256, 256, 0, stream>>>(
      W_ih, W_hh, b_ih, b_hh, W_att, W_embed, Bg, Bx, Ba, We, bcomb);
  sort_kernel<<<1, B_, 0, stream>>>(lengths, perm);
  if (use_gx) {
    gx_kernel<<<B_, 256, 0, stream>>>(features, Bx, gxw);
    mol_kernel<1><<<NBLK, NT, 0, stream>>>(
        features, lengths, perm, Bg, Ba, We, bcomb,
        W_final, b_final, q0, c0, r0, gxw, out);
  } else {
    mol_kernel<0><<<NBLK, NT, 0, stream>>>(
        features, lengths, perm, Bg, Ba, We, bcomb,
        W_final, b_final, q0, c0, r0, gxw, out);
  }
}